// Round 8
// baseline (201.223 us; speedup 1.0000x reference)
//
#include <hip/hip_runtime.h>
#include <hip/hip_bf16.h>

typedef unsigned short u16;
typedef __attribute__((ext_vector_type(8))) short short8;
typedef __attribute__((ext_vector_type(4))) float f32x4;

#define BATCH_ 32

static __device__ __forceinline__ float b2f(u16 u) {
  union { unsigned int i; float f; } v; v.i = ((unsigned int)u) << 16; return v.f;
}
static __device__ __forceinline__ u16 f2b(float x) {
  unsigned int i = __float_as_uint(x);
  unsigned int r = (i + 0x7fffu + ((i >> 16) & 1u)) >> 16;
  return (u16)r;
}

#define GCAST(p) ((const __attribute__((address_space(1))) void*)(p))
#define LCAST(p) ((__attribute__((address_space(3))) void*)(p))

// ---- elementwise f32 -> bf16 (n % 4 == 0)
__global__ __launch_bounds__(256) void cvt_bf16(const float* __restrict__ src,
                                                u16* __restrict__ dst, int n) {
  int i = (blockIdx.x * 256 + threadIdx.x) * 4;
  if (i >= n) return;
  float4 v = *(const float4*)(src + i);
  ushort4 o;
  o.x = f2b(v.x); o.y = f2b(v.y); o.z = f2b(v.z); o.w = f2b(v.w);
  *(ushort4*)(dst + i) = o;
}

// ---- transpose f32 [R][C] -> bf16 [C][R]
__global__ __launch_bounds__(256) void transpose_cvt(const float* __restrict__ src,
                                                     u16* __restrict__ dst, int R, int C) {
  __shared__ float tile[32][33];
  int c0 = blockIdx.x * 32, r0 = blockIdx.y * 32;
  int tx = threadIdx.x & 31, ty = threadIdx.x >> 5;
  #pragma unroll
  for (int i = 0; i < 32; i += 8)
    tile[ty + i][tx] = src[(long long)(r0 + ty + i) * C + c0 + tx];
  __syncthreads();
  #pragma unroll
  for (int i = 0; i < 32; i += 8)
    dst[(long long)(c0 + ty + i) * R + r0 + tx] = f2b(tile[tx][ty + i]);
}

// ---- scaled[b][k][o] = otherT[k][o] * fix[b][o]   (bf16)
__global__ __launch_bounds__(256) void build_scaled(const u16* __restrict__ oT,
                                                    const float* __restrict__ fix,
                                                    u16* __restrict__ out) {
  long long i4 = (long long)blockIdx.x * 256 + threadIdx.x; // group of 4 along o
  int o = (int)(i4 & 511) * 4;
  long long bk = i4 >> 9;            // b*512 + kk
  int b = (int)(bk >> 9);
  int kk = (int)(bk & 511);
  ushort4 v = *(const ushort4*)(oT + (long long)kk * 2048 + o);
  float4 f = *(const float4*)(fix + (long long)b * 2048 + o);
  ushort4 r;
  r.x = f2b(b2f(v.x) * f.x); r.y = f2b(b2f(v.y) * f.y);
  r.z = f2b(b2f(v.z) * f.z); r.w = f2b(b2f(v.w) * f.w);
  *(ushort4*)(out + bk * 2048 + o) = r;
}

// ---- masked row softmax: P[row][:] = softmax(S[row][:] * 1/sqrt(512), mask)
__global__ __launch_bounds__(256) void softmax_mask(const float* __restrict__ S,
                                                    const int* __restrict__ mask,
                                                    u16* __restrict__ P, int N) {
  const float scale = 0.044194173824159216f; // 1/sqrt(512)
  int row = blockIdx.x;
  int t = threadIdx.x;
  long long base = (long long)row * N;
  float vals[8]; int msk[8];
  float mx = -3.0e38f;
  #pragma unroll
  for (int i = 0; i < 8; ++i) {
    int c = t + i * 256;
    float s = S[base + c] * scale;
    int m = mask[base + c];
    vals[i] = s; msk[i] = m;
    if (!m) mx = fmaxf(mx, s);
  }
  #pragma unroll
  for (int off = 32; off; off >>= 1) mx = fmaxf(mx, __shfl_xor(mx, off));
  __shared__ float sred[4];
  if ((t & 63) == 0) sred[t >> 6] = mx;
  __syncthreads();
  mx = fmaxf(fmaxf(sred[0], sred[1]), fmaxf(sred[2], sred[3]));
  __syncthreads();
  float e[8]; float sum = 0.f;
  #pragma unroll
  for (int i = 0; i < 8; ++i) {
    e[i] = msk[i] ? 0.f : __expf(vals[i] - mx);
    sum += e[i];
  }
  #pragma unroll
  for (int off = 32; off; off >>= 1) sum += __shfl_xor(sum, off);
  if ((t & 63) == 0) sred[t >> 6] = sum;
  __syncthreads();
  sum = sred[0] + sred[1] + sred[2] + sred[3];
  float inv = (sum > 0.f) ? (1.f / sum) : 0.f;
  #pragma unroll
  for (int i = 0; i < 8; ++i) {
    int c = t + i * 256;
    P[base + c] = f2b(e[i] * inv);
  }
}

// ========== r2-proven 128x128 / BK=32 GEMM (small GEMMs: Q|K proj, S) ======
// EPI 0: outB = bf16(C + bias[col]); dual-weight via second half of grid.y
// EPI 1: outF = C (f32)
#define GBM 128
#define GBN 128
#define GBK 32

template<int EPI>
__global__ __launch_bounds__(256) void gemm_lds(
    const u16* __restrict__ A, const u16* __restrict__ Bt,
    const float* __restrict__ bias,
    const u16* __restrict__ Bt2, const float* __restrict__ bias2,
    float* __restrict__ outF, u16* __restrict__ outB,
    int M, int N, int K) {
  __shared__ u16 sA[GBM * GBK];
  __shared__ u16 sB[GBN * GBK];
  int m0 = blockIdx.y * GBM, n0 = blockIdx.x * GBN;
  if (EPI == 0) {
    if (2 * blockIdx.y >= gridDim.y) { Bt = Bt2; bias = bias2; }
  }
  int t = threadIdx.x;
  int wid = t >> 6, lane = t & 63;
  int wm = (wid >> 1) * 64, wn = (wid & 1) * 64;
  int lr = lane & 15, lq = lane >> 4;
  int srow = lane >> 2, schunk = (lane & 3) * 8;

  f32x4 acc[4][4];
  #pragma unroll
  for (int i = 0; i < 4; ++i)
    #pragma unroll
    for (int j = 0; j < 4; ++j)
      acc[i][j] = (f32x4){0.f, 0.f, 0.f, 0.f};

  const u16* gA = A + (long long)(m0 + wid * 32 + srow) * K + schunk;
  const u16* gB = Bt + (long long)(n0 + wid * 32 + srow) * K + schunk;
  u16* lA = &sA[(wid * 32) * GBK];
  u16* lB = &sB[(wid * 32) * GBK];
  const long long rowskip = (long long)16 * K;

  for (int k0 = 0; k0 < K; k0 += GBK) {
    __builtin_amdgcn_global_load_lds(GCAST(gA + k0),           LCAST(lA),            16, 0, 0);
    __builtin_amdgcn_global_load_lds(GCAST(gA + k0 + rowskip), LCAST(lA + 16 * GBK), 16, 0, 0);
    __builtin_amdgcn_global_load_lds(GCAST(gB + k0),           LCAST(lB),            16, 0, 0);
    __builtin_amdgcn_global_load_lds(GCAST(gB + k0 + rowskip), LCAST(lB + 16 * GBK), 16, 0, 0);
    __syncthreads();
    short8 af[4], bf[4];
    #pragma unroll
    for (int i = 0; i < 4; ++i)
      af[i] = *(const short8*)&sA[(wm + i * 16 + lr) * GBK + lq * 8];
    #pragma unroll
    for (int j = 0; j < 4; ++j)
      bf[j] = *(const short8*)&sB[(wn + j * 16 + lr) * GBK + lq * 8];
    #pragma unroll
    for (int i = 0; i < 4; ++i)
      #pragma unroll
      for (int j = 0; j < 4; ++j)
        acc[i][j] = __builtin_amdgcn_mfma_f32_16x16x32_bf16(af[i], bf[j], acc[i][j], 0, 0, 0);
    __syncthreads();
  }

  #pragma unroll
  for (int i = 0; i < 4; ++i) {
    #pragma unroll
    for (int j = 0; j < 4; ++j) {
      int col = n0 + wn + j * 16 + lr;
      #pragma unroll
      for (int r = 0; r < 4; ++r) {
        int row = m0 + wm + i * 16 + lq * 4 + r;
        float v = acc[i][j][r];
        if (EPI == 0) {
          outB[(long long)row * N + col] = f2b(v + bias[col]);
        } else {
          outF[(long long)row * N + col] = v;
        }
      }
    }
  }
}

// ========== m201-style 8-barrier phase GEMM: 256x256, BK=64, ring-2 ========
// C[m][n] = sum_k A[m][k]*Bt[n][k]; epilogue scatter n -> (b=n>>9, k=n&511).
// 512 thr = 8 waves (2M x 4N), wave tile 128x64. LDS: 2 bufs x (A 32K | B 32K).
// Per K=64 tile, 4 phases, each: {ds_reads | 2 gload_lds stage -> nb |
// s_barrier | lgkmcnt(0) | setprio(1) 16-MFMA setprio(0) | s_barrier}.
// Read plan (no re-reads, 24 b128/wave/tile):
//   ph0: A[0..3]h0, B h0 -> MFMA i0-3 x j0-3 (h0)
//   ph1: A[4..7]h0, B h1 -> MFMA i4-7 (h0)
//   ph2: A[0..3]h1, A[4..7]h1 -> MFMA i0-3 (h1)
//   ph3: (no reads)         -> MFMA i4-7 (h1); vmcnt(0) at tile end (loads
//        issued ~2500cy earlier -> drain is free); ring-2 W/R separation
//        >= 2 barriers everywhere.
// Swizzle: slot(h) = ((h*4+lq) ^ (lr&7)); inverse on staging source (XOR
// involution, both sides -- rule #21). Balanced over all 32 banks.
__global__ __launch_bounds__(512, 2) void gemm_ring(
    const u16* __restrict__ A, const u16* __restrict__ Bt,
    float* __restrict__ outF, int M, int N, int K) {
  __shared__ u16 lds[2 * 32768];   // [buf][A 16384 | B 16384] u16 = 128 KiB

  // XCD-chunked swizzle: XCD owns contiguous N-chunk, M fastest inside.
  int nwg = gridDim.x * gridDim.y;
  int wg = blockIdx.y * gridDim.x + blockIdx.x;
  int cpx = nwg >> 3;
  int swz = (wg & 7) * cpx + (wg >> 3);
  int bx = swz & 7, by = swz >> 3;          // gridDim.x == 8
  int m0 = bx * 256, n0 = by * 256;

  int t = threadIdx.x;
  int w = t >> 6, lane = t & 63;
  int wr = w >> 2, wc = w & 3;              // wave tile: 128 rows x 64 cols
  int lr = lane & 15, lq = lane >> 4;

  // read slot offsets (u16) for K-half h
  const int s0 = ((lq) ^ (lr & 7)) * 8;
  const int s1 = ((4 + lq) ^ (lr & 7)) * 8;
  const int arow = wr * 128 + lr;            // A frag base row
  const int brow = wc * 64 + lr;             // B frag base row

  // staging: per 64-row call, thread t covers row (t>>3), slot (t&7);
  // source chunk inverse-swizzled.
  int sr = t >> 3;
  int sch = ((t & 7) ^ (sr & 7)) * 8;
  const u16* pA = A + (long long)(m0 + sr) * K + sch;
  const u16* pB = Bt + (long long)(n0 + sr) * K + sch;
  const int ldst = (t >> 6) * 512;           // wave-uniform base within a call
  const long long rsk = (long long)64 * K;   // 64-row source skip

  f32x4 acc[8][4];
  #pragma unroll
  for (int i = 0; i < 8; ++i)
    #pragma unroll
    for (int j = 0; j < 4; ++j)
      acc[i][j] = (f32x4){0.f, 0.f, 0.f, 0.f};

  const int NT = K >> 6;   // K/64 tiles (=32)

  // stage call: op 0=A 1=B, quarter c (rows c*64..c*64+63), tile KT -> buf NB
  #define STG(OP, C, KT, NB)                                                          \
    __builtin_amdgcn_global_load_lds(                                                 \
      GCAST(((OP) ? pB : pA) + (long long)(C) * rsk + (long long)(KT) * 64),          \
      LCAST(&lds[(NB) * 32768 + (OP) * 16384 + (C) * 4096 + ldst]), 16, 0, 0)

  #define RDA(DST, IB, SH, BUF) {                                                     \
    _Pragma("unroll")                                                                 \
    for (int ii = 0; ii < 4; ++ii)                                                    \
      DST[ii] = *(const short8*)&lds[(BUF) * 32768 + (arow + ((IB) + ii) * 16) * 64 + (SH)]; }

  #define RDB(DST, SH, BUF) {                                                         \
    _Pragma("unroll")                                                                 \
    for (int jj = 0; jj < 4; ++jj)                                                    \
      DST[jj] = *(const short8*)&lds[(BUF) * 32768 + 16384 + (brow + jj * 16) * 64 + (SH)]; }

  #define MF16(AF, BF, IB) {                                                          \
    __builtin_amdgcn_s_setprio(1);                                                    \
    _Pragma("unroll")                                                                 \
    for (int ii = 0; ii < 4; ++ii)                                                    \
      _Pragma("unroll")                                                               \
      for (int jj = 0; jj < 4; ++jj)                                                  \
        acc[(IB) + ii][jj] =                                                          \
          __builtin_amdgcn_mfma_f32_16x16x32_bf16(AF[ii], BF[jj], acc[(IB) + ii][jj], 0, 0, 0); \
    __builtin_amdgcn_s_setprio(0); }

  #define PH_SYNC() do {                                                              \
    __builtin_amdgcn_sched_barrier(0);                                                \
    __builtin_amdgcn_s_barrier();                                                     \
    asm volatile("s_waitcnt lgkmcnt(0)" ::: "memory");                                \
    __builtin_amdgcn_sched_barrier(0);                                                \
  } while (0)

  short8 aA[4], aB[4], aC[4], aD[4], b0[4], b1[4];

  // prologue: stage tile 0 -> buf 0 (8 calls); drain; barrier
  #pragma unroll
  for (int c = 0; c < 4; ++c) { STG(0, c, 0, 0); STG(1, c, 0, 0); }
  asm volatile("s_waitcnt vmcnt(0)" ::: "memory");
  __builtin_amdgcn_s_barrier();
  __builtin_amdgcn_sched_barrier(0);

  for (int kt = 0; kt < NT; ++kt) {
    const int buf = kt & 1, nb = buf ^ 1;
    const int st = (kt + 1 < NT);
    // ---- ph0
    RDA(aA, 0, s0, buf); RDB(b0, s0, buf);
    if (st) { STG(0, 0, kt + 1, nb); STG(0, 1, kt + 1, nb); }
    PH_SYNC();
    MF16(aA, b0, 0);
    __builtin_amdgcn_sched_barrier(0);
    __builtin_amdgcn_s_barrier();
    // ---- ph1
    RDA(aB, 4, s0, buf); RDB(b1, s1, buf);
    if (st) { STG(0, 2, kt + 1, nb); STG(0, 3, kt + 1, nb); }
    PH_SYNC();
    MF16(aB, b0, 4);
    __builtin_amdgcn_sched_barrier(0);
    __builtin_amdgcn_s_barrier();
    // ---- ph2
    RDA(aC, 0, s1, buf); RDA(aD, 4, s1, buf);
    if (st) { STG(1, 0, kt + 1, nb); STG(1, 1, kt + 1, nb); }
    PH_SYNC();
    MF16(aC, b1, 0);
    __builtin_amdgcn_sched_barrier(0);
    __builtin_amdgcn_s_barrier();
    // ---- ph3 (no reads)
    if (st) { STG(1, 2, kt + 1, nb); STG(1, 3, kt + 1, nb); }
    __builtin_amdgcn_sched_barrier(0);
    __builtin_amdgcn_s_barrier();
    __builtin_amdgcn_sched_barrier(0);
    MF16(aD, b1, 4);
    __builtin_amdgcn_sched_barrier(0);
    asm volatile("s_waitcnt vmcnt(0)" ::: "memory");  // next tile resident
    __builtin_amdgcn_s_barrier();
    __builtin_amdgcn_sched_barrier(0);
  }

  #undef STG
  #undef RDA
  #undef RDB
  #undef MF16
  #undef PH_SYNC

  // epilogue: scatter cols -> per-batch layout
  #pragma unroll
  for (int i = 0; i < 8; ++i) {
    #pragma unroll
    for (int j = 0; j < 4; ++j) {
      int col = n0 + wc * 64 + j * 16 + lr;
      int b = col >> 9, kc = col & 511;
      float* ob = outF + (long long)b * ((long long)M * 512) + kc;
      #pragma unroll
      for (int r = 0; r < 4; ++r) {
        int row = m0 + wr * 128 + i * 16 + lq * 4 + r;
        ob[(long long)row * 512] = acc[i][j][r];
      }
    }
  }
}

// ============ fallback (round-1 kernel) for small-ws path ============
#define BMT 128
#define BNT 128
#define BKT 32
#define LDSP 40

template<int MODE>
__global__ __launch_bounds__(256) void gemm_bt(
    const u16* __restrict__ A, const u16* __restrict__ Bt,
    const float* __restrict__ bias, const float* __restrict__ fixmat,
    float* __restrict__ outF, u16* __restrict__ outB,
    int M, int N, int K, long long out_batch_stride, int bt_batch_stride) {
  __shared__ u16 sA[BMT][LDSP];
  __shared__ u16 sB[BNT][LDSP];
  int b = blockIdx.z;
  const u16* Bt_b = Bt + (long long)b * bt_batch_stride;
  const float* fixrow = (MODE == 2) ? (fixmat + (long long)b * K) : nullptr;
  float* out_b = (MODE != 0) ? (outF + (long long)b * out_batch_stride) : nullptr;

  int m0 = blockIdx.y * BMT, n0 = blockIdx.x * BNT;
  int t = threadIdx.x;
  int wid = t >> 6, lane = t & 63;
  int wm = (wid >> 1) * 64, wn = (wid & 1) * 64;
  int lr = lane & 15, lq = lane >> 4;

  f32x4 acc[4][4];
  #pragma unroll
  for (int i = 0; i < 4; ++i)
    #pragma unroll
    for (int j = 0; j < 4; ++j)
      acc[i][j] = (f32x4){0.f, 0.f, 0.f, 0.f};

  int srow = t >> 1, scg = (t & 1) * 16;

  for (int k0 = 0; k0 < K; k0 += BKT) {
    {
      const u16* src = A + (long long)(m0 + srow) * K + k0 + scg;
      short8 v0 = *(const short8*)(src);
      short8 v1 = *(const short8*)(src + 8);
      *(short8*)&sA[srow][scg] = v0;
      *(short8*)&sA[srow][scg + 8] = v1;
    }
    {
      const u16* src = Bt_b + (long long)(n0 + srow) * K + k0 + scg;
      short8 v0 = *(const short8*)(src);
      short8 v1 = *(const short8*)(src + 8);
      if (MODE == 2) {
        u16* p0 = (u16*)&v0; u16* p1 = (u16*)&v1;
        #pragma unroll
        for (int j = 0; j < 8; ++j) {
          p0[j] = f2b(b2f(p0[j]) * fixrow[k0 + scg + j]);
          p1[j] = f2b(b2f(p1[j]) * fixrow[k0 + scg + 8 + j]);
        }
      }
      *(short8*)&sB[srow][scg] = v0;
      *(short8*)&sB[srow][scg + 8] = v1;
    }
    __syncthreads();
    short8 af[4], bf[4];
    #pragma unroll
    for (int i = 0; i < 4; ++i)
      af[i] = *(const short8*)&sA[wm + i * 16 + lr][lq * 8];
    #pragma unroll
    for (int j = 0; j < 4; ++j)
      bf[j] = *(const short8*)&sB[wn + j * 16 + lr][lq * 8];
    #pragma unroll
    for (int i = 0; i < 4; ++i)
      #pragma unroll
      for (int j = 0; j < 4; ++j)
        acc[i][j] = __builtin_amdgcn_mfma_f32_16x16x32_bf16(af[i], bf[j], acc[i][j], 0, 0, 0);
    __syncthreads();
  }

  #pragma unroll
  for (int i = 0; i < 4; ++i) {
    #pragma unroll
    for (int j = 0; j < 4; ++j) {
      int col = n0 + wn + j * 16 + lr;
      #pragma unroll
      for (int r = 0; r < 4; ++r) {
        int row = m0 + wm + i * 16 + lq * 4 + r;
        float v = acc[i][j][r];
        if (MODE == 0) {
          v += bias[col];
          outB[(long long)row * N + col] = f2b(v);
        } else {
          out_b[(long long)row * N + col] = v;
        }
      }
    }
  }
}

extern "C" void kernel_launch(void* const* d_in, const int* in_sizes, int n_in,
                              void* d_out, int out_size, void* d_ws, size_t ws_size,
                              hipStream_t stream) {
  const float* main_feat  = (const float*)d_in[0];
  const float* other_feat = (const float*)d_in[1];
  const float* fix_feat   = (const float*)d_in[2];
  const int*   mask       = (const int*)d_in[3];
  const float* Wq         = (const float*)d_in[4];
  const float* bq         = (const float*)d_in[5];
  const float* Wk         = (const float*)d_in[6];
  const float* bk         = (const float*)d_in[7];
  float* out = (float*)d_out;

  char* ws = (char*)d_ws;
  const size_t OFF_MAINB  = 0;          // 2 MiB  (mainB and otherB contiguous!)
  const size_t OFF_OTHERB = 2097152;    // 2 MiB
  const size_t OFF_WQB    = 4194304;    // 512 KiB
  const size_t OFF_WKB    = 4718592;    // 512 KiB
  const size_t OFF_QB     = 5242880;    // 2 MiB  (QB and KB contiguous!)
  const size_t OFF_KB     = 7340032;    // 2 MiB
  const size_t OFF_OTB    = 9437184;    // 2 MiB  (otherT bf16 [512][2048])
  const size_t OFF_P      = 11534336;   // 8 MiB  (P bf16 [2048][2048])
  const size_t OFF_S      = 19922944;   // 16 MiB (S f32 [2048][2048])
  const size_t OFF_SCALED = 36700160;   // 64 MiB (scaled bf16 [32][512][2048])
  const size_t NEED_SCALED = OFF_SCALED + (size_t)BATCH_ * 512 * 2048 * 2;

  u16* mainB  = (u16*)(ws + OFF_MAINB);
  u16* otherB = (u16*)(ws + OFF_OTHERB);
  u16* WqB    = (u16*)(ws + OFF_WQB);
  u16* WkB    = (u16*)(ws + OFF_WKB);
  u16* QB     = (u16*)(ws + OFF_QB);
  u16* KB     = (u16*)(ws + OFF_KB);
  u16* oTB    = (u16*)(ws + OFF_OTB);
  u16* P      = (u16*)(ws + OFF_P);
  float* S    = (float*)(ws + OFF_S);
  u16* scaled = (u16*)(ws + OFF_SCALED);
  bool use_scaled = (ws_size >= NEED_SCALED);

  // 1) bf16 conversions
  cvt_bf16<<<1024, 256, 0, stream>>>(main_feat, mainB, 2048 * 512);
  cvt_bf16<<<1024, 256, 0, stream>>>(other_feat, otherB, 2048 * 512);
  cvt_bf16<<<256, 256, 0, stream>>>(Wq, WqB, 512 * 512);
  cvt_bf16<<<256, 256, 0, stream>>>(Wk, WkB, 512 * 512);
  // 2) otherT bf16 [512][2048]
  transpose_cvt<<<dim3(16, 64), 256, 0, stream>>>(other_feat, oTB, 2048, 512);

  if (use_scaled) {
    // 3) fused Q|K projection: M=4096 (rows 0..2047 -> Wq/bq, 2048.. -> Wk/bk)
    gemm_lds<0><<<dim3(4, 32), 256, 0, stream>>>(mainB, WqB, bq, WkB, bk,
        nullptr, QB, 4096, 512, 512);
    // 4) S = Q @ K^T (f32, unscaled; softmax applies 1/sqrt(512))
    gemm_lds<1><<<dim3(16, 16), 256, 0, stream>>>(QB, KB, nullptr, nullptr, nullptr,
        S, nullptr, 2048, 2048, 512);
    // 5) masked softmax -> P bf16
    softmax_mask<<<2048, 256, 0, stream>>>(S, mask, P, 2048);
    // 6) scaled[b][k][o] = otherT[k][o]*fix[b][o], viewed as Bt [16384][2048]
    build_scaled<<<32768, 256, 0, stream>>>(oTB, fix_feat, scaled);
    // 7) single big phase-pipelined GEMM: out[b][m][k] via col scatter
    gemm_ring<<<dim3(8, 64), 512, 0, stream>>>(P, scaled, out, 2048, 16384, 2048);
  } else {
    // fallback: round-1 path (no 64MB scaled buffer)
    gemm_bt<0><<<dim3(4, 16, 1), 256, 0, stream>>>(mainB, WqB, bq, nullptr,
        nullptr, QB, 2048, 512, 512, 0, 0);
    gemm_bt<0><<<dim3(4, 16, 1), 256, 0, stream>>>(otherB, WkB, bk, nullptr,
        nullptr, KB, 2048, 512, 512, 0, 0);
    gemm_bt<1><<<dim3(16, 16, 1), 256, 0, stream>>>(QB, KB, nullptr, nullptr,
        S, nullptr, 2048, 2048, 512, 0, 0);
    softmax_mask<<<2048, 256, 0, stream>>>(S, mask, P, 2048);
    gemm_bt<2><<<dim3(4, 16, BATCH_), 256, 0, stream>>>(P, oTB, nullptr, fix_feat,
        out, nullptr, 2048, 512, 2048, 1048576LL, 0);
  }
}

// Round 9
// 194.604 us; speedup vs baseline: 1.0340x; 1.0340x over previous
//
#include <hip/hip_runtime.h>
#include <hip/hip_bf16.h>

typedef unsigned short u16;
typedef __attribute__((ext_vector_type(8))) short short8;
typedef __attribute__((ext_vector_type(4))) float f32x4;
typedef __attribute__((ext_vector_type(16))) float f32x16;

#define BATCH_ 32

static __device__ __forceinline__ float b2f(u16 u) {
  union { unsigned int i; float f; } v; v.i = ((unsigned int)u) << 16; return v.f;
}
static __device__ __forceinline__ u16 f2b(float x) {
  unsigned int i = __float_as_uint(x);
  unsigned int r = (i + 0x7fffu + ((i >> 16) & 1u)) >> 16;
  return (u16)r;
}

#define GCAST(p) ((const __attribute__((address_space(1))) void*)(p))
#define LCAST(p) ((__attribute__((address_space(3))) void*)(p))

// ---- elementwise f32 -> bf16 (n % 4 == 0)
__global__ __launch_bounds__(256) void cvt_bf16(const float* __restrict__ src,
                                                u16* __restrict__ dst, int n) {
  int i = (blockIdx.x * 256 + threadIdx.x) * 4;
  if (i >= n) return;
  float4 v = *(const float4*)(src + i);
  ushort4 o;
  o.x = f2b(v.x); o.y = f2b(v.y); o.z = f2b(v.z); o.w = f2b(v.w);
  *(ushort4*)(dst + i) = o;
}

// ---- transpose f32 [R][C] -> bf16 [C][R]
__global__ __launch_bounds__(256) void transpose_cvt(const float* __restrict__ src,
                                                     u16* __restrict__ dst, int R, int C) {
  __shared__ float tile[32][33];
  int c0 = blockIdx.x * 32, r0 = blockIdx.y * 32;
  int tx = threadIdx.x & 31, ty = threadIdx.x >> 5;
  #pragma unroll
  for (int i = 0; i < 32; i += 8)
    tile[ty + i][tx] = src[(long long)(r0 + ty + i) * C + c0 + tx];
  __syncthreads();
  #pragma unroll
  for (int i = 0; i < 32; i += 8)
    dst[(long long)(c0 + ty + i) * R + r0 + tx] = f2b(tile[tx][ty + i]);
}

// ---- scaled[b][k][o] = otherT[k][o] * fix[b][o]   (bf16)
__global__ __launch_bounds__(256) void build_scaled(const u16* __restrict__ oT,
                                                    const float* __restrict__ fix,
                                                    u16* __restrict__ out) {
  long long i4 = (long long)blockIdx.x * 256 + threadIdx.x; // group of 4 along o
  int o = (int)(i4 & 511) * 4;
  long long bk = i4 >> 9;            // b*512 + kk
  int b = (int)(bk >> 9);
  int kk = (int)(bk & 511);
  ushort4 v = *(const ushort4*)(oT + (long long)kk * 2048 + o);
  float4 f = *(const float4*)(fix + (long long)b * 2048 + o);
  ushort4 r;
  r.x = f2b(b2f(v.x) * f.x); r.y = f2b(b2f(v.y) * f.y);
  r.z = f2b(b2f(v.z) * f.z); r.w = f2b(b2f(v.w) * f.w);
  *(ushort4*)(out + bk * 2048 + o) = r;
}

// ---- masked row softmax: P[row][:] = softmax(S[row][:] * 1/sqrt(512), mask)
__global__ __launch_bounds__(256) void softmax_mask(const float* __restrict__ S,
                                                    const int* __restrict__ mask,
                                                    u16* __restrict__ P, int N) {
  const float scale = 0.044194173824159216f; // 1/sqrt(512)
  int row = blockIdx.x;
  int t = threadIdx.x;
  long long base = (long long)row * N;
  float vals[8]; int msk[8];
  float mx = -3.0e38f;
  #pragma unroll
  for (int i = 0; i < 8; ++i) {
    int c = t + i * 256;
    float s = S[base + c] * scale;
    int m = mask[base + c];
    vals[i] = s; msk[i] = m;
    if (!m) mx = fmaxf(mx, s);
  }
  #pragma unroll
  for (int off = 32; off; off >>= 1) mx = fmaxf(mx, __shfl_xor(mx, off));
  __shared__ float sred[4];
  if ((t & 63) == 0) sred[t >> 6] = mx;
  __syncthreads();
  mx = fmaxf(fmaxf(sred[0], sred[1]), fmaxf(sred[2], sred[3]));
  __syncthreads();
  float e[8]; float sum = 0.f;
  #pragma unroll
  for (int i = 0; i < 8; ++i) {
    e[i] = msk[i] ? 0.f : __expf(vals[i] - mx);
    sum += e[i];
  }
  #pragma unroll
  for (int off = 32; off; off >>= 1) sum += __shfl_xor(sum, off);
  if ((t & 63) == 0) sred[t >> 6] = sum;
  __syncthreads();
  sum = sred[0] + sred[1] + sred[2] + sred[3];
  float inv = (sum > 0.f) ? (1.f / sum) : 0.f;
  #pragma unroll
  for (int i = 0; i < 8; ++i) {
    int c = t + i * 256;
    P[base + c] = f2b(e[i] * inv);
  }
}

// ========== r2-proven 128x128 / BK=32 GEMM (small GEMMs: Q|K proj, S) ======
// EPI 0: outB = bf16(C + bias[col]); dual-weight via second half of grid.y
// EPI 1: outF = C (f32)
#define GBM 128
#define GBN 128
#define GBK 32

template<int EPI>
__global__ __launch_bounds__(256) void gemm_lds(
    const u16* __restrict__ A, const u16* __restrict__ Bt,
    const float* __restrict__ bias,
    const u16* __restrict__ Bt2, const float* __restrict__ bias2,
    float* __restrict__ outF, u16* __restrict__ outB,
    int M, int N, int K) {
  __shared__ u16 sA[GBM * GBK];
  __shared__ u16 sB[GBN * GBK];
  int m0 = blockIdx.y * GBM, n0 = blockIdx.x * GBN;
  if (EPI == 0) {
    if (2 * blockIdx.y >= gridDim.y) { Bt = Bt2; bias = bias2; }
  }
  int t = threadIdx.x;
  int wid = t >> 6, lane = t & 63;
  int wm = (wid >> 1) * 64, wn = (wid & 1) * 64;
  int lr = lane & 15, lq = lane >> 4;
  int srow = lane >> 2, schunk = (lane & 3) * 8;

  f32x4 acc[4][4];
  #pragma unroll
  for (int i = 0; i < 4; ++i)
    #pragma unroll
    for (int j = 0; j < 4; ++j)
      acc[i][j] = (f32x4){0.f, 0.f, 0.f, 0.f};

  const u16* gA = A + (long long)(m0 + wid * 32 + srow) * K + schunk;
  const u16* gB = Bt + (long long)(n0 + wid * 32 + srow) * K + schunk;
  u16* lA = &sA[(wid * 32) * GBK];
  u16* lB = &sB[(wid * 32) * GBK];
  const long long rowskip = (long long)16 * K;

  for (int k0 = 0; k0 < K; k0 += GBK) {
    __builtin_amdgcn_global_load_lds(GCAST(gA + k0),           LCAST(lA),            16, 0, 0);
    __builtin_amdgcn_global_load_lds(GCAST(gA + k0 + rowskip), LCAST(lA + 16 * GBK), 16, 0, 0);
    __builtin_amdgcn_global_load_lds(GCAST(gB + k0),           LCAST(lB),            16, 0, 0);
    __builtin_amdgcn_global_load_lds(GCAST(gB + k0 + rowskip), LCAST(lB + 16 * GBK), 16, 0, 0);
    __syncthreads();
    short8 af[4], bf[4];
    #pragma unroll
    for (int i = 0; i < 4; ++i)
      af[i] = *(const short8*)&sA[(wm + i * 16 + lr) * GBK + lq * 8];
    #pragma unroll
    for (int j = 0; j < 4; ++j)
      bf[j] = *(const short8*)&sB[(wn + j * 16 + lr) * GBK + lq * 8];
    #pragma unroll
    for (int i = 0; i < 4; ++i)
      #pragma unroll
      for (int j = 0; j < 4; ++j)
        acc[i][j] = __builtin_amdgcn_mfma_f32_16x16x32_bf16(af[i], bf[j], acc[i][j], 0, 0, 0);
    __syncthreads();
  }

  #pragma unroll
  for (int i = 0; i < 4; ++i) {
    #pragma unroll
    for (int j = 0; j < 4; ++j) {
      int col = n0 + wn + j * 16 + lr;
      #pragma unroll
      for (int r = 0; r < 4; ++r) {
        int row = m0 + wm + i * 16 + lq * 4 + r;
        float v = acc[i][j][r];
        if (EPI == 0) {
          outB[(long long)row * N + col] = f2b(v + bias[col]);
        } else {
          outF[(long long)row * N + col] = v;
        }
      }
    }
  }
}

// ========== ring-4 counted-vmcnt 256x256 GEMM, 32x32x16 MFMA, reg prefetch =
// R7 skeleton (proven 137.5us) with the MFMA shape swapped to 32x32x16:
// same LDS bytes/iter (12 b128/wave), half the MFMA instructions (16/wave),
// ~15% faster matrix pipe. Wave tile 128x64 = 4x2 tiles of 32x32.
// A frag: row=lane&31, k=(lane>>5)*8+e (analog of the verified 16x16 map);
// C/D: col=lane&31, row=(reg&3)+8*(reg>>2)+4*(lane>>5)  [m74/m101].
// LDS swizzle: read slot s ^ ((row>>1)&3), inverse pre-applied on the
// staging source (both-sides involution, rule #21). Bank-quad balanced.
#define SGB __builtin_amdgcn_sched_group_barrier
// masks: MFMA=0x008, VMEM_READ=0x020, DS_READ=0x100

__global__ __launch_bounds__(512, 2) void gemm_ring(
    const u16* __restrict__ A, const u16* __restrict__ Bt,
    float* __restrict__ outF, int M, int N, int K) {
  __shared__ u16 lds[4][2][8192];   // [ring][A/B][row*32 + slot*8] = 128 KiB

  // XCD-chunked swizzle: XCD owns contiguous N-chunk, M fastest inside.
  int nwg = gridDim.x * gridDim.y;
  int wg = blockIdx.y * gridDim.x + blockIdx.x;
  int cpx = nwg >> 3;
  int swz = (wg & 7) * cpx + (wg >> 3);
  int bx = swz & 7, by = swz >> 3;          // gridDim.x == 8
  int m0 = bx * 256, n0 = by * 256;

  int t = threadIdx.x;
  int w = t >> 6, lane = t & 63;
  int wr = w >> 2, wc = w & 3;              // wave tile: 128 rows x 64 cols
  int l31 = lane & 31, lhi = lane >> 5;
  // swizzled slot offsets (u16) for k-half 0/1: desired slot = h*2 + lhi
  const int sw0 = ((0 * 2 + lhi) ^ ((l31 >> 1) & 3)) * 8;
  const int sw1 = ((1 * 2 + lhi) ^ ((l31 >> 1) & 3)) * 8;

  // staging source (pre-swizzled): thread t covers row (t>>2), slot (t&3)
  int srow = t >> 2;                                  // 0..127
  int sgc = (((srow >> 1) & 3) ^ (t & 3)) * 8;        // inverse-swizzled chunk
  const u16* pA0 = A + (long long)(m0 + srow) * K + sgc;
  const u16* pA1 = pA0 + (long long)128 * K;
  const u16* pB0 = Bt + (long long)(n0 + srow) * K + sgc;
  const u16* pB1 = pB0 + (long long)128 * K;
  const int lbase = (w * 16) * 32;           // wave-uniform LDS base (u16)

  f32x16 acc[4][2];
  #pragma unroll
  for (int i = 0; i < 4; ++i)
    #pragma unroll
    for (int j = 0; j < 2; ++j)
      #pragma unroll
      for (int r = 0; r < 16; ++r)
        acc[i][j][r] = 0.f;

  const int NT = K >> 5;   // K/32 tiles (=64)

  #define STAGE_TILE(KT, SB)                                                          \
    do {                                                                              \
      long long cofs = (long long)(KT) * 32;                                          \
      __builtin_amdgcn_global_load_lds(GCAST(pA0 + cofs), LCAST(&lds[SB][0][lbase]),            16, 0, 0); \
      __builtin_amdgcn_global_load_lds(GCAST(pA1 + cofs), LCAST(&lds[SB][0][lbase + 128 * 32]), 16, 0, 0); \
      __builtin_amdgcn_global_load_lds(GCAST(pB0 + cofs), LCAST(&lds[SB][1][lbase]),            16, 0, 0); \
      __builtin_amdgcn_global_load_lds(GCAST(pB1 + cofs), LCAST(&lds[SB][1][lbase + 128 * 32]), 16, 0, 0); \
    } while (0)

  // 12 b128 reads: A 4 tile-rows x 2 k-halves, B 2 col-tiles x 2 k-halves
  #define RD_FRAGS(AF, BF, BUF) {                                                     \
    _Pragma("unroll")                                                                 \
    for (int i = 0; i < 4; ++i) {                                                     \
      AF[i * 2]     = *(const short8*)&lds[BUF][0][(wr * 128 + i * 32 + l31) * 32 + sw0]; \
      AF[i * 2 + 1] = *(const short8*)&lds[BUF][0][(wr * 128 + i * 32 + l31) * 32 + sw1]; \
    }                                                                                 \
    _Pragma("unroll")                                                                 \
    for (int j = 0; j < 2; ++j) {                                                     \
      BF[j * 2]     = *(const short8*)&lds[BUF][1][(wc * 64 + j * 32 + l31) * 32 + sw0]; \
      BF[j * 2 + 1] = *(const short8*)&lds[BUF][1][(wc * 64 + j * 32 + l31) * 32 + sw1]; \
    } }

  #define MFMA_NP(AF, BF) {                                                           \
    _Pragma("unroll")                                                                 \
    for (int h = 0; h < 2; ++h)                                                       \
      _Pragma("unroll")                                                               \
      for (int i = 0; i < 4; ++i)                                                     \
        _Pragma("unroll")                                                             \
        for (int j = 0; j < 2; ++j)                                                   \
          acc[i][j] = __builtin_amdgcn_mfma_f32_32x32x16_bf16(                        \
              AF[i * 2 + h], BF[j * 2 + h], acc[i][j], 0, 0, 0); }

  #define MFMA_BLK(AF, BF) {                                                          \
    __builtin_amdgcn_s_setprio(1);                                                    \
    MFMA_NP(AF, BF);                                                                  \
    __builtin_amdgcn_s_setprio(0); }

  // issue-interleave: MFMA2 | {DS2 MFMA2}x4 | VMEM4 | {DS2 MFMA2}x2 | MFMA2
  #define SGB_TAIL() {                                                                \
    SGB(0x008, 2, 0);                                                                 \
    SGB(0x100, 2, 0); SGB(0x008, 2, 0);                                               \
    SGB(0x100, 2, 0); SGB(0x008, 2, 0);                                               \
    SGB(0x100, 2, 0); SGB(0x008, 2, 0);                                               \
    SGB(0x100, 2, 0); SGB(0x008, 2, 0);                                               \
    SGB(0x020, 4, 0);                                                                 \
    SGB(0x100, 2, 0); SGB(0x008, 2, 0);                                               \
    SGB(0x100, 2, 0); SGB(0x008, 2, 0);                                               \
    SGB(0x008, 2, 0); }

  short8 afA[8], bfA[4], afB[8], bfB[4];

  // prologue: stage tiles 0,1,2 (12 loads); vmcnt(4) -> tiles 0,1 resident
  STAGE_TILE(0, 0);
  STAGE_TILE(1, 1);
  STAGE_TILE(2, 2);
  asm volatile("s_waitcnt vmcnt(4)" ::: "memory");
  __builtin_amdgcn_s_barrier();
  __builtin_amdgcn_sched_barrier(0);
  RD_FRAGS(afA, bfA, 0);                     // regs <- tile 0

  // steady state: 2 iters per body; invariant at iter kt entry:
  //   tiles <= kt+1 LDS-resident, tile kt+2's 4 loads outstanding.
  for (int kt = 0; kt + 4 < NT; kt += 2) {
    // ---- iter kt (cur = A)
    RD_FRAGS(afB, bfB, ((kt + 1) & 3));      // regs <- tile kt+1 (resident)
    STAGE_TILE(kt + 3, ((kt + 3) & 3));      // outstanding: kt+2, kt+3 (8)
    MFMA_NP(afA, bfA);                       // tile kt; interleaved via SGB
    SGB_TAIL();
    asm volatile("s_waitcnt vmcnt(4)" ::: "memory");   // tile kt+2 resident
    __builtin_amdgcn_s_barrier();
    __builtin_amdgcn_sched_barrier(0);
    // ---- iter kt+1 (cur = B)
    RD_FRAGS(afA, bfA, ((kt + 2) & 3));
    STAGE_TILE(kt + 4, ((kt + 4) & 3));
    MFMA_NP(afB, bfB);
    SGB_TAIL();
    asm volatile("s_waitcnt vmcnt(4)" ::: "memory");
    __builtin_amdgcn_s_barrier();
    __builtin_amdgcn_sched_barrier(0);
  }

  // tail: iters NT-4 .. NT-1 (steady loop ended at iter NT-5, parity even)
  // iter NT-4 (cur = A)
  RD_FRAGS(afB, bfB, ((NT - 3) & 3));
  STAGE_TILE(NT - 1, ((NT - 1) & 3));
  __builtin_amdgcn_sched_barrier(0);
  MFMA_BLK(afA, bfA);
  __builtin_amdgcn_sched_barrier(0);
  asm volatile("s_waitcnt vmcnt(4)" ::: "memory");     // tile NT-2 resident
  __builtin_amdgcn_s_barrier();
  __builtin_amdgcn_sched_barrier(0);
  // iter NT-3 (cur = B)
  RD_FRAGS(afA, bfA, ((NT - 2) & 3));
  __builtin_amdgcn_sched_barrier(0);
  MFMA_BLK(afB, bfB);
  __builtin_amdgcn_sched_barrier(0);
  asm volatile("s_waitcnt vmcnt(0)" ::: "memory");     // tile NT-1 resident
  __builtin_amdgcn_s_barrier();
  __builtin_amdgcn_sched_barrier(0);
  // iter NT-2 (cur = A)
  RD_FRAGS(afB, bfB, ((NT - 1) & 3));
  __builtin_amdgcn_sched_barrier(0);
  MFMA_BLK(afA, bfA);
  // iter NT-1 (cur = B) -- pure register MFMA, no barrier needed
  MFMA_BLK(afB, bfB);

  #undef STAGE_TILE
  #undef RD_FRAGS
  #undef MFMA_NP
  #undef MFMA_BLK
  #undef SGB_TAIL

  // epilogue: scatter cols -> per-batch layout (32x32 C/D mapping)
  #pragma unroll
  for (int i = 0; i < 4; ++i) {
    #pragma unroll
    for (int j = 0; j < 2; ++j) {
      int col = n0 + wc * 64 + j * 32 + l31;
      int b = col >> 9, kc = col & 511;
      float* ob = outF + (long long)b * ((long long)M * 512) + kc;
      #pragma unroll
      for (int r = 0; r < 16; ++r) {
        int row = m0 + wr * 128 + i * 32 + (r & 3) + 8 * (r >> 2) + 4 * lhi;
        ob[(long long)row * 512] = acc[i][j][r];
      }
    }
  }
}

// ============ fallback (round-1 kernel) for small-ws path ============
#define BMT 128
#define BNT 128
#define BKT 32
#define LDSP 40

template<int MODE>
__global__ __launch_bounds__(256) void gemm_bt(
    const u16* __restrict__ A, const u16* __restrict__ Bt,
    const float* __restrict__ bias, const float* __restrict__ fixmat,
    float* __restrict__ outF, u16* __restrict__ outB,
    int M, int N, int K, long long out_batch_stride, int bt_batch_stride) {
  __shared__ u16 sA[BMT][LDSP];
  __shared__ u16 sB[BNT][LDSP];
  int b = blockIdx.z;
  const u16* Bt_b = Bt + (long long)b * bt_batch_stride;
  const float* fixrow = (MODE == 2) ? (fixmat + (long long)b * K) : nullptr;
  float* out_b = (MODE != 0) ? (outF + (long long)b * out_batch_stride) : nullptr;

  int m0 = blockIdx.y * BMT, n0 = blockIdx.x * BNT;
  int t = threadIdx.x;
  int wid = t >> 6, lane = t & 63;
  int wm = (wid >> 1) * 64, wn = (wid & 1) * 64;
  int lr = lane & 15, lq = lane >> 4;

  f32x4 acc[4][4];
  #pragma unroll
  for (int i = 0; i < 4; ++i)
    #pragma unroll
    for (int j = 0; j < 4; ++j)
      acc[i][j] = (f32x4){0.f, 0.f, 0.f, 0.f};

  int srow = t >> 1, scg = (t & 1) * 16;

  for (int k0 = 0; k0 < K; k0 += BKT) {
    {
      const u16* src = A + (long long)(m0 + srow) * K + k0 + scg;
      short8 v0 = *(const short8*)(src);
      short8 v1 = *(const short8*)(src + 8);
      *(short8*)&sA[srow][scg] = v0;
      *(short8*)&sA[srow][scg + 8] = v1;
    }
    {
      const u16* src = Bt_b + (long long)(n0 + srow) * K + k0 + scg;
      short8 v0 = *(const short8*)(src);
      short8 v1 = *(const short8*)(src + 8);
      if (MODE == 2) {
        u16* p0 = (u16*)&v0; u16* p1 = (u16*)&v1;
        #pragma unroll
        for (int j = 0; j < 8; ++j) {
          p0[j] = f2b(b2f(p0[j]) * fixrow[k0 + scg + j]);
          p1[j] = f2b(b2f(p1[j]) * fixrow[k0 + scg + 8 + j]);
        }
      }
      *(short8*)&sB[srow][scg] = v0;
      *(short8*)&sB[srow][scg + 8] = v1;
    }
    __syncthreads();
    short8 af[4], bf[4];
    #pragma unroll
    for (int i = 0; i < 4; ++i)
      af[i] = *(const short8*)&sA[wm + i * 16 + lr][lq * 8];
    #pragma unroll
    for (int j = 0; j < 4; ++j)
      bf[j] = *(const short8*)&sB[wn + j * 16 + lr][lq * 8];
    #pragma unroll
    for (int i = 0; i < 4; ++i)
      #pragma unroll
      for (int j = 0; j < 4; ++j)
        acc[i][j] = __builtin_amdgcn_mfma_f32_16x16x32_bf16(af[i], bf[j], acc[i][j], 0, 0, 0);
    __syncthreads();
  }

  #pragma unroll
  for (int i = 0; i < 4; ++i) {
    #pragma unroll
    for (int j = 0; j < 4; ++j) {
      int col = n0 + wn + j * 16 + lr;
      #pragma unroll
      for (int r = 0; r < 4; ++r) {
        int row = m0 + wm + i * 16 + lq * 4 + r;
        float v = acc[i][j][r];
        if (MODE == 0) {
          v += bias[col];
          outB[(long long)row * N + col] = f2b(v);
        } else {
          out_b[(long long)row * N + col] = v;
        }
      }
    }
  }
}

extern "C" void kernel_launch(void* const* d_in, const int* in_sizes, int n_in,
                              void* d_out, int out_size, void* d_ws, size_t ws_size,
                              hipStream_t stream) {
  const float* main_feat  = (const float*)d_in[0];
  const float* other_feat = (const float*)d_in[1];
  const float* fix_feat   = (const float*)d_in[2];
  const int*   mask       = (const int*)d_in[3];
  const float* Wq         = (const float*)d_in[4];
  const float* bq         = (const float*)d_in[5];
  const float* Wk         = (const float*)d_in[6];
  const float* bk         = (const float*)d_in[7];
  float* out = (float*)d_out;

  char* ws = (char*)d_ws;
  const size_t OFF_MAINB  = 0;          // 2 MiB  (mainB and otherB contiguous!)
  const size_t OFF_OTHERB = 2097152;    // 2 MiB
  const size_t OFF_WQB    = 4194304;    // 512 KiB
  const size_t OFF_WKB    = 4718592;    // 512 KiB
  const size_t OFF_QB     = 5242880;    // 2 MiB  (QB and KB contiguous!)
  const size_t OFF_KB     = 7340032;    // 2 MiB
  const size_t OFF_OTB    = 9437184;    // 2 MiB  (otherT bf16 [512][2048])
  const size_t OFF_P      = 11534336;   // 8 MiB  (P bf16 [2048][2048])
  const size_t OFF_S      = 19922944;   // 16 MiB (S f32 [2048][2048])
  const size_t OFF_SCALED = 36700160;   // 64 MiB (scaled bf16 [32][512][2048])
  const size_t NEED_SCALED = OFF_SCALED + (size_t)BATCH_ * 512 * 2048 * 2;

  u16* mainB  = (u16*)(ws + OFF_MAINB);
  u16* otherB = (u16*)(ws + OFF_OTHERB);
  u16* WqB    = (u16*)(ws + OFF_WQB);
  u16* WkB    = (u16*)(ws + OFF_WKB);
  u16* QB     = (u16*)(ws + OFF_QB);
  u16* KB     = (u16*)(ws + OFF_KB);
  u16* oTB    = (u16*)(ws + OFF_OTB);
  u16* P      = (u16*)(ws + OFF_P);
  float* S    = (float*)(ws + OFF_S);
  u16* scaled = (u16*)(ws + OFF_SCALED);
  bool use_scaled = (ws_size >= NEED_SCALED);

  // 1) bf16 conversions
  cvt_bf16<<<1024, 256, 0, stream>>>(main_feat, mainB, 2048 * 512);
  cvt_bf16<<<1024, 256, 0, stream>>>(other_feat, otherB, 2048 * 512);
  cvt_bf16<<<256, 256, 0, stream>>>(Wq, WqB, 512 * 512);
  cvt_bf16<<<256, 256, 0, stream>>>(Wk, WkB, 512 * 512);
  // 2) otherT bf16 [512][2048]
  transpose_cvt<<<dim3(16, 64), 256, 0, stream>>>(other_feat, oTB, 2048, 512);

  if (use_scaled) {
    // 3) fused Q|K projection: M=4096 (rows 0..2047 -> Wq/bq, 2048.. -> Wk/bk)
    gemm_lds<0><<<dim3(4, 32), 256, 0, stream>>>(mainB, WqB, bq, WkB, bk,
        nullptr, QB, 4096, 512, 512);
    // 4) S = Q @ K^T (f32, unscaled; softmax applies 1/sqrt(512))
    gemm_lds<1><<<dim3(16, 16), 256, 0, stream>>>(QB, KB, nullptr, nullptr, nullptr,
        S, nullptr, 2048, 2048, 512);
    // 5) masked softmax -> P bf16
    softmax_mask<<<2048, 256, 0, stream>>>(S, mask, P, 2048);
    // 6) scaled[b][k][o] = otherT[k][o]*fix[b][o], viewed as Bt [16384][2048]
    build_scaled<<<32768, 256, 0, stream>>>(oTB, fix_feat, scaled);
    // 7) single big ring-pipelined GEMM: out[b][m][k] via col scatter
    gemm_ring<<<dim3(8, 64), 512, 0, stream>>>(P, scaled, out, 2048, 16384, 2048);
  } else {
    // fallback: round-1 path (no 64MB scaled buffer)
    gemm_bt<0><<<dim3(4, 16, 1), 256, 0, stream>>>(mainB, WqB, bq, nullptr,
        nullptr, QB, 2048, 512, 512, 0, 0);
    gemm_bt<0><<<dim3(4, 16, 1), 256, 0, stream>>>(otherB, WkB, bk, nullptr,
        nullptr, KB, 2048, 512, 512, 0, 0);
    gemm_bt<1><<<dim3(16, 16, 1), 256, 0, stream>>>(QB, KB, nullptr, nullptr,
        S, nullptr, 2048, 2048, 512, 0, 0);
    softmax_mask<<<2048, 256, 0, stream>>>(S, mask, P, 2048);
    gemm_bt<2><<<dim3(4, 16, BATCH_), 256, 0, stream>>>(P, oTB, nullptr, fix_feat,
        out, nullptr, 2048, 512, 2048, 1048576LL, 0);
  }
}

// Round 10
// 189.704 us; speedup vs baseline: 1.0607x; 1.0258x over previous
//
#include <hip/hip_runtime.h>
#include <hip/hip_bf16.h>

typedef unsigned short u16;
typedef __attribute__((ext_vector_type(8))) short short8;
typedef __attribute__((ext_vector_type(4))) float f32x4;

#define BATCH_ 32

static __device__ __forceinline__ float b2f(u16 u) {
  union { unsigned int i; float f; } v; v.i = ((unsigned int)u) << 16; return v.f;
}
static __device__ __forceinline__ u16 f2b(float x) {
  unsigned int i = __float_as_uint(x);
  unsigned int r = (i + 0x7fffu + ((i >> 16) & 1u)) >> 16;
  return (u16)r;
}

#define GCAST(p) ((const __attribute__((address_space(1))) void*)(p))
#define LCAST(p) ((__attribute__((address_space(3))) void*)(p))

// ---- elementwise f32 -> bf16 (n % 4 == 0)
__global__ __launch_bounds__(256) void cvt_bf16(const float* __restrict__ src,
                                                u16* __restrict__ dst, int n) {
  int i = (blockIdx.x * 256 + threadIdx.x) * 4;
  if (i >= n) return;
  float4 v = *(const float4*)(src + i);
  ushort4 o;
  o.x = f2b(v.x); o.y = f2b(v.y); o.z = f2b(v.z); o.w = f2b(v.w);
  *(ushort4*)(dst + i) = o;
}

// ---- transpose f32 [R][C] -> bf16 [C][R]
__global__ __launch_bounds__(256) void transpose_cvt(const float* __restrict__ src,
                                                     u16* __restrict__ dst, int R, int C) {
  __shared__ float tile[32][33];
  int c0 = blockIdx.x * 32, r0 = blockIdx.y * 32;
  int tx = threadIdx.x & 31, ty = threadIdx.x >> 5;
  #pragma unroll
  for (int i = 0; i < 32; i += 8)
    tile[ty + i][tx] = src[(long long)(r0 + ty + i) * C + c0 + tx];
  __syncthreads();
  #pragma unroll
  for (int i = 0; i < 32; i += 8)
    dst[(long long)(c0 + ty + i) * R + r0 + tx] = f2b(tile[tx][ty + i]);
}

// ---- scaled[b][k][o] = otherT[k][o] * fix[b][o]   (bf16)
__global__ __launch_bounds__(256) void build_scaled(const u16* __restrict__ oT,
                                                    const float* __restrict__ fix,
                                                    u16* __restrict__ out) {
  long long i4 = (long long)blockIdx.x * 256 + threadIdx.x; // group of 4 along o
  int o = (int)(i4 & 511) * 4;
  long long bk = i4 >> 9;            // b*512 + kk
  int b = (int)(bk >> 9);
  int kk = (int)(bk & 511);
  ushort4 v = *(const ushort4*)(oT + (long long)kk * 2048 + o);
  float4 f = *(const float4*)(fix + (long long)b * 2048 + o);
  ushort4 r;
  r.x = f2b(b2f(v.x) * f.x); r.y = f2b(b2f(v.y) * f.y);
  r.z = f2b(b2f(v.z) * f.z); r.w = f2b(b2f(v.w) * f.w);
  *(ushort4*)(out + bk * 2048 + o) = r;
}

// ---- masked row softmax: P[row][:] = softmax(S[row][:] * 1/sqrt(512), mask)
__global__ __launch_bounds__(256) void softmax_mask(const float* __restrict__ S,
                                                    const int* __restrict__ mask,
                                                    u16* __restrict__ P, int N) {
  const float scale = 0.044194173824159216f; // 1/sqrt(512)
  int row = blockIdx.x;
  int t = threadIdx.x;
  long long base = (long long)row * N;
  float vals[8]; int msk[8];
  float mx = -3.0e38f;
  #pragma unroll
  for (int i = 0; i < 8; ++i) {
    int c = t + i * 256;
    float s = S[base + c] * scale;
    int m = mask[base + c];
    vals[i] = s; msk[i] = m;
    if (!m) mx = fmaxf(mx, s);
  }
  #pragma unroll
  for (int off = 32; off; off >>= 1) mx = fmaxf(mx, __shfl_xor(mx, off));
  __shared__ float sred[4];
  if ((t & 63) == 0) sred[t >> 6] = mx;
  __syncthreads();
  mx = fmaxf(fmaxf(sred[0], sred[1]), fmaxf(sred[2], sred[3]));
  __syncthreads();
  float e[8]; float sum = 0.f;
  #pragma unroll
  for (int i = 0; i < 8; ++i) {
    e[i] = msk[i] ? 0.f : __expf(vals[i] - mx);
    sum += e[i];
  }
  #pragma unroll
  for (int off = 32; off; off >>= 1) sum += __shfl_xor(sum, off);
  if ((t & 63) == 0) sred[t >> 6] = sum;
  __syncthreads();
  sum = sred[0] + sred[1] + sred[2] + sred[3];
  float inv = (sum > 0.f) ? (1.f / sum) : 0.f;
  #pragma unroll
  for (int i = 0; i < 8; ++i) {
    int c = t + i * 256;
    P[base + c] = f2b(e[i] * inv);
  }
}

// ========== r2-proven 128x128 / BK=32 GEMM (small GEMMs: Q|K proj, S) ======
#define GBM 128
#define GBN 128
#define GBK 32

template<int EPI>
__global__ __launch_bounds__(256) void gemm_lds(
    const u16* __restrict__ A, const u16* __restrict__ Bt,
    const float* __restrict__ bias,
    const u16* __restrict__ Bt2, const float* __restrict__ bias2,
    float* __restrict__ outF, u16* __restrict__ outB,
    int M, int N, int K) {
  __shared__ u16 sA[GBM * GBK];
  __shared__ u16 sB[GBN * GBK];
  int m0 = blockIdx.y * GBM, n0 = blockIdx.x * GBN;
  if (EPI == 0) {
    if (2 * blockIdx.y >= gridDim.y) { Bt = Bt2; bias = bias2; }
  }
  int t = threadIdx.x;
  int wid = t >> 6, lane = t & 63;
  int wm = (wid >> 1) * 64, wn = (wid & 1) * 64;
  int lr = lane & 15, lq = lane >> 4;
  int srow = lane >> 2, schunk = (lane & 3) * 8;

  f32x4 acc[4][4];
  #pragma unroll
  for (int i = 0; i < 4; ++i)
    #pragma unroll
    for (int j = 0; j < 4; ++j)
      acc[i][j] = (f32x4){0.f, 0.f, 0.f, 0.f};

  const u16* gA = A + (long long)(m0 + wid * 32 + srow) * K + schunk;
  const u16* gB = Bt + (long long)(n0 + wid * 32 + srow) * K + schunk;
  u16* lA = &sA[(wid * 32) * GBK];
  u16* lB = &sB[(wid * 32) * GBK];
  const long long rowskip = (long long)16 * K;

  for (int k0 = 0; k0 < K; k0 += GBK) {
    __builtin_amdgcn_global_load_lds(GCAST(gA + k0),           LCAST(lA),            16, 0, 0);
    __builtin_amdgcn_global_load_lds(GCAST(gA + k0 + rowskip), LCAST(lA + 16 * GBK), 16, 0, 0);
    __builtin_amdgcn_global_load_lds(GCAST(gB + k0),           LCAST(lB),            16, 0, 0);
    __builtin_amdgcn_global_load_lds(GCAST(gB + k0 + rowskip), LCAST(lB + 16 * GBK), 16, 0, 0);
    __syncthreads();
    short8 af[4], bf[4];
    #pragma unroll
    for (int i = 0; i < 4; ++i)
      af[i] = *(const short8*)&sA[(wm + i * 16 + lr) * GBK + lq * 8];
    #pragma unroll
    for (int j = 0; j < 4; ++j)
      bf[j] = *(const short8*)&sB[(wn + j * 16 + lr) * GBK + lq * 8];
    #pragma unroll
    for (int i = 0; i < 4; ++i)
      #pragma unroll
      for (int j = 0; j < 4; ++j)
        acc[i][j] = __builtin_amdgcn_mfma_f32_16x16x32_bf16(af[i], bf[j], acc[i][j], 0, 0, 0);
    __syncthreads();
  }

  #pragma unroll
  for (int i = 0; i < 4; ++i) {
    #pragma unroll
    for (int j = 0; j < 4; ++j) {
      int col = n0 + wn + j * 16 + lr;
      #pragma unroll
      for (int r = 0; r < 4; ++r) {
        int row = m0 + wm + i * 16 + lq * 4 + r;
        float v = acc[i][j][r];
        if (EPI == 0) {
          outB[(long long)row * N + col] = f2b(v + bias[col]);
        } else {
          outF[(long long)row * N + col] = v;
        }
      }
    }
  }
}

// ========== m201-faithful 8-phase GEMM: 256x256, BK=64, K-half regions =====
// C[m][n] = sum_k A[m][k]*Bt[n][k]; epilogue scatter n -> (b=n>>9, k=n&511).
// 512 thr = 8 waves (2M x 4N), wave tile 128x64, 16x16x32 MFMA.
// LDS: 8 regions x 16KB = 128 KiB: [A|B] x [tile-parity 0|1] x [k-half 0|1],
// each 256 rows x 32 k u16. Iter t handles tiles a=2t (parity0), a+1 (par1).
// Phases (reads | 1 half-tile stage | bar | lgkmcnt(0) | 16 MFMA | bar):
//  ph1: rd B(a,k0)+A(a,i0-3,k0); stg A(a+1)k1   ph5: rd B(a1,k0)+A; stg A(a+2)k1
//  ph2: rd A(a,i4-7,k0);         stg B(a+1)k1   ph6: rd A;          stg B(a+2)k1
//  ph3: rd B(a,k1)+A(a,i0-3,k1); stg A(a+2)k0   ph7: rd B(a1,k1)+A; stg A(a+3)k0
//  ph4: rd A(a,i4-7,k1);         stg B(a+2)k0   ph8: rd A;          stg B(a+3)k0
// vmcnt(8) before the end-barrier of ph2/4/6/8 ONLY (never 0 in-loop):
// retired stages are always >=4.5 phases old (HBM hidden); every stage's
// target region had its last read >=2 barriers earlier (audited).
// Tail iter: no ph3-8 stages; vmcnt(4)@ph4, vmcnt(0)@ph6.
// Swizzle: read slot = lq ^ ((lr>>1)&3) (2-way = free, R5/R7-proven);
// inverse involution on staging source chunk (rule #21).
__global__ __launch_bounds__(512, 2) void gemm_ring(
    const u16* __restrict__ A, const u16* __restrict__ Bt,
    float* __restrict__ outF, int M, int N, int K) {
  __shared__ u16 lds[65536];   // 128 KiB

  // XCD-chunked swizzle: XCD owns contiguous N-chunk, M fastest inside.
  int nwg = gridDim.x * gridDim.y;
  int wg = blockIdx.y * gridDim.x + blockIdx.x;
  int cpx = nwg >> 3;
  int swz = (wg & 7) * cpx + (wg >> 3);
  int bx = swz & 7, by = swz >> 3;          // gridDim.x == 8
  int m0 = bx * 256, n0 = by * 256;

  int t = threadIdx.x;
  int w = t >> 6, lane = t & 63;
  int wr = w >> 2, wc = w & 3;              // wave tile: 128 rows x 64 cols
  int lr = lane & 15, lq = lane >> 4;
  const int rsw = (lq ^ ((lr >> 1) & 3)) * 8;      // swizzled read slot (u16)
  const int aoff = (wr * 128 + lr) * 32 + rsw;     // A row base offset
  const int boff = (wc * 64 + lr) * 32 + rsw;      // B row base offset

  // staging: thread t covers row (t>>2) (+128 for call 1), slot (t&3),
  // source chunk inverse-swizzled.
  int srow = t >> 2;                                  // 0..127
  int sgc = ((t & 3) ^ ((srow >> 1) & 3)) * 8;        // involution
  const u16* pA = A + (long long)(m0 + srow) * K + sgc;
  const u16* pB = Bt + (long long)(n0 + srow) * K + sgc;
  const long long rsk128 = (long long)128 * K;        // call-1 source skip
  const int w512 = w * 512;                           // wave-uniform LDS base

  f32x4 acc[8][4];
  #pragma unroll
  for (int i = 0; i < 8; ++i)
    #pragma unroll
    for (int j = 0; j < 4; ++j)
      acc[i][j] = (f32x4){0.f, 0.f, 0.f, 0.f};

  // region base (u16): A: ((par*2+kh)*8192), B: 32768 + same
  #define STG2(OP, KTILE, KH) do {                                                    \
    const u16* sp_ = (OP) ? pB : pA;                                                  \
    long long so_ = (long long)(KTILE) * 64 + (KH) * 32;                              \
    int db_ = ((OP) ? 32768 : 0) + ((((KTILE) & 1) * 2 + (KH)) * 8192) + w512;        \
    __builtin_amdgcn_global_load_lds(GCAST(sp_ + so_),          LCAST(&lds[db_]),        16, 0, 0); \
    __builtin_amdgcn_global_load_lds(GCAST(sp_ + so_ + rsk128), LCAST(&lds[db_ + 4096]), 16, 0, 0); \
  } while (0)

  #define RD_A(IB, PAR, KH) {                                                         \
    _Pragma("unroll")                                                                 \
    for (int ii = 0; ii < 4; ++ii)                                                    \
      af[ii] = *(const short8*)&lds[(((PAR) * 2 + (KH)) * 8192) + aoff + ((IB) + ii) * 512]; }

  #define RD_B(PAR, KH) {                                                             \
    _Pragma("unroll")                                                                 \
    for (int jj = 0; jj < 4; ++jj)                                                    \
      bf[jj] = *(const short8*)&lds[32768 + (((PAR) * 2 + (KH)) * 8192) + boff + jj * 512]; }

  #define MF16(IB) {                                                                  \
    __builtin_amdgcn_s_setprio(1);                                                    \
    _Pragma("unroll")                                                                 \
    for (int ii = 0; ii < 4; ++ii)                                                    \
      _Pragma("unroll")                                                               \
      for (int jj = 0; jj < 4; ++jj)                                                  \
        acc[(IB) + ii][jj] =                                                          \
          __builtin_amdgcn_mfma_f32_16x16x32_bf16(af[ii], bf[jj], acc[(IB) + ii][jj], 0, 0, 0); \
    __builtin_amdgcn_s_setprio(0); }

  #define SB __builtin_amdgcn_sched_barrier(0)
  #define BAR __builtin_amdgcn_s_barrier()
  #define LGKM0 asm volatile("s_waitcnt lgkmcnt(0)" ::: "memory")

  short8 af[4], bf[4];
  const int NIT = (K >> 6) >> 1;   // 16 double-tile iters

  // prologue: A0k0,B0k0,A0k1,B0k1,A1k0,B1k0 (12 calls); vmcnt(8) -> tile0 k0 in
  STG2(0, 0, 0); STG2(1, 0, 0);
  STG2(0, 0, 1); STG2(1, 0, 1);
  STG2(0, 1, 0); STG2(1, 1, 0);
  asm volatile("s_waitcnt vmcnt(8)" ::: "memory");
  BAR; SB;

  for (int t2 = 0; t2 < NIT; ++t2) {
    const int a = t2 * 2;
    const bool lastit = (t2 == NIT - 1);
    // ---- ph1: B(a,k0)->regs, A(a,0-3,k0); stage A(a+1)k1
    RD_B(0, 0); RD_A(0, 0, 0);
    STG2(0, a + 1, 1);
    SB; BAR; LGKM0; SB;
    MF16(0);
    SB; BAR; SB;
    // ---- ph2: A(a,4-7,k0); stage B(a+1)k1; vmcnt(8)
    RD_A(4, 0, 0);
    STG2(1, a + 1, 1);
    SB; BAR; LGKM0; SB;
    MF16(4);
    SB;
    asm volatile("s_waitcnt vmcnt(8)" ::: "memory");
    BAR; SB;
    // ---- ph3: B(a,k1), A(a,0-3,k1); stage A(a+2)k0
    RD_B(0, 1); RD_A(0, 0, 1);
    if (!lastit) STG2(0, a + 2, 0);
    SB; BAR; LGKM0; SB;
    MF16(0);
    SB; BAR; SB;
    // ---- ph4: A(a,4-7,k1); stage B(a+2)k0; vmcnt
    RD_A(4, 0, 1);
    if (!lastit) STG2(1, a + 2, 0);
    SB; BAR; LGKM0; SB;
    MF16(4);
    SB;
    if (!lastit) { asm volatile("s_waitcnt vmcnt(8)" ::: "memory"); }
    else         { asm volatile("s_waitcnt vmcnt(4)" ::: "memory"); }
    BAR; SB;
    // ---- ph5: B(a+1,k0), A(a+1,0-3,k0); stage A(a+2)k1
    RD_B(1, 0); RD_A(0, 1, 0);
    if (!lastit) STG2(0, a + 2, 1);
    SB; BAR; LGKM0; SB;
    MF16(0);
    SB; BAR; SB;
    // ---- ph6: A(a+1,4-7,k0); stage B(a+2)k1; vmcnt
    RD_A(4, 1, 0);
    if (!lastit) STG2(1, a + 2, 1);
    SB; BAR; LGKM0; SB;
    MF16(4);
    SB;
    if (!lastit) { asm volatile("s_waitcnt vmcnt(8)" ::: "memory"); }
    else         { asm volatile("s_waitcnt vmcnt(0)" ::: "memory"); }
    BAR; SB;
    // ---- ph7: B(a+1,k1), A(a+1,0-3,k1); stage A(a+3)k0
    RD_B(1, 1); RD_A(0, 1, 1);
    if (!lastit) STG2(0, a + 3, 0);
    SB; BAR; LGKM0; SB;
    MF16(0);
    SB; BAR; SB;
    // ---- ph8: A(a+1,4-7,k1); stage B(a+3)k0; vmcnt(8)
    RD_A(4, 1, 1);
    if (!lastit) STG2(1, a + 3, 0);
    SB; BAR; LGKM0; SB;
    MF16(4);
    SB;
    if (!lastit) { asm volatile("s_waitcnt vmcnt(8)" ::: "memory"); BAR; SB; }
  }

  #undef STG2
  #undef RD_A
  #undef RD_B
  #undef MF16
  #undef SB
  #undef BAR
  #undef LGKM0

  // epilogue: scatter cols -> per-batch layout
  #pragma unroll
  for (int i = 0; i < 8; ++i) {
    #pragma unroll
    for (int j = 0; j < 4; ++j) {
      int col = n0 + wc * 64 + j * 16 + lr;
      int b = col >> 9, kc = col & 511;
      float* ob = outF + (long long)b * ((long long)M * 512) + kc;
      #pragma unroll
      for (int r = 0; r < 4; ++r) {
        int row = m0 + wr * 128 + i * 16 + lq * 4 + r;
        ob[(long long)row * 512] = acc[i][j][r];
      }
    }
  }
}

// ============ fallback (round-1 kernel) for small-ws path ============
#define BMT 128
#define BNT 128
#define BKT 32
#define LDSP 40

template<int MODE>
__global__ __launch_bounds__(256) void gemm_bt(
    const u16* __restrict__ A, const u16* __restrict__ Bt,
    const float* __restrict__ bias, const float* __restrict__ fixmat,
    float* __restrict__ outF, u16* __restrict__ outB,
    int M, int N, int K, long long out_batch_stride, int bt_batch_stride) {
  __shared__ u16 sA[BMT][LDSP];
  __shared__ u16 sB[BNT][LDSP];
  int b = blockIdx.z;
  const u16* Bt_b = Bt + (long long)b * bt_batch_stride;
  const float* fixrow = (MODE == 2) ? (fixmat + (long long)b * K) : nullptr;
  float* out_b = (MODE != 0) ? (outF + (long long)b * out_batch_stride) : nullptr;

  int m0 = blockIdx.y * BMT, n0 = blockIdx.x * BNT;
  int t = threadIdx.x;
  int wid = t >> 6, lane = t & 63;
  int wm = (wid >> 1) * 64, wn = (wid & 1) * 64;
  int lr = lane & 15, lq = lane >> 4;

  f32x4 acc[4][4];
  #pragma unroll
  for (int i = 0; i < 4; ++i)
    #pragma unroll
    for (int j = 0; j < 4; ++j)
      acc[i][j] = (f32x4){0.f, 0.f, 0.f, 0.f};

  int srow = t >> 1, scg = (t & 1) * 16;

  for (int k0 = 0; k0 < K; k0 += BKT) {
    {
      const u16* src = A + (long long)(m0 + srow) * K + k0 + scg;
      short8 v0 = *(const short8*)(src);
      short8 v1 = *(const short8*)(src + 8);
      *(short8*)&sA[srow][scg] = v0;
      *(short8*)&sA[srow][scg + 8] = v1;
    }
    {
      const u16* src = Bt_b + (long long)(n0 + srow) * K + k0 + scg;
      short8 v0 = *(const short8*)(src);
      short8 v1 = *(const short8*)(src + 8);
      if (MODE == 2) {
        u16* p0 = (u16*)&v0; u16* p1 = (u16*)&v1;
        #pragma unroll
        for (int j = 0; j < 8; ++j) {
          p0[j] = f2b(b2f(p0[j]) * fixrow[k0 + scg + j]);
          p1[j] = f2b(b2f(p1[j]) * fixrow[k0 + scg + 8 + j]);
        }
      }
      *(short8*)&sB[srow][scg] = v0;
      *(short8*)&sB[srow][scg + 8] = v1;
    }
    __syncthreads();
    short8 af[4], bf[4];
    #pragma unroll
    for (int i = 0; i < 4; ++i)
      af[i] = *(const short8*)&sA[wm + i * 16 + lr][lq * 8];
    #pragma unroll
    for (int j = 0; j < 4; ++j)
      bf[j] = *(const short8*)&sB[wn + j * 16 + lr][lq * 8];
    #pragma unroll
    for (int i = 0; i < 4; ++i)
      #pragma unroll
      for (int j = 0; j < 4; ++j)
        acc[i][j] = __builtin_amdgcn_mfma_f32_16x16x32_bf16(af[i], bf[j], acc[i][j], 0, 0, 0);
    __syncthreads();
  }

  #pragma unroll
  for (int i = 0; i < 4; ++i) {
    #pragma unroll
    for (int j = 0; j < 4; ++j) {
      int col = n0 + wn + j * 16 + lr;
      #pragma unroll
      for (int r = 0; r < 4; ++r) {
        int row = m0 + wm + i * 16 + lq * 4 + r;
        float v = acc[i][j][r];
        if (MODE == 0) {
          v += bias[col];
          outB[(long long)row * N + col] = f2b(v);
        } else {
          out_b[(long long)row * N + col] = v;
        }
      }
    }
  }
}

extern "C" void kernel_launch(void* const* d_in, const int* in_sizes, int n_in,
                              void* d_out, int out_size, void* d_ws, size_t ws_size,
                              hipStream_t stream) {
  const float* main_feat  = (const float*)d_in[0];
  const float* other_feat = (const float*)d_in[1];
  const float* fix_feat   = (const float*)d_in[2];
  const int*   mask       = (const int*)d_in[3];
  const float* Wq         = (const float*)d_in[4];
  const float* bq         = (const float*)d_in[5];
  const float* Wk         = (const float*)d_in[6];
  const float* bk         = (const float*)d_in[7];
  float* out = (float*)d_out;

  char* ws = (char*)d_ws;
  const size_t OFF_MAINB  = 0;
  const size_t OFF_OTHERB = 2097152;
  const size_t OFF_WQB    = 4194304;
  const size_t OFF_WKB    = 4718592;
  const size_t OFF_QB     = 5242880;
  const size_t OFF_KB     = 7340032;
  const size_t OFF_OTB    = 9437184;
  const size_t OFF_P      = 11534336;
  const size_t OFF_S      = 19922944;
  const size_t OFF_SCALED = 36700160;
  const size_t NEED_SCALED = OFF_SCALED + (size_t)BATCH_ * 512 * 2048 * 2;

  u16* mainB  = (u16*)(ws + OFF_MAINB);
  u16* otherB = (u16*)(ws + OFF_OTHERB);
  u16* WqB    = (u16*)(ws + OFF_WQB);
  u16* WkB    = (u16*)(ws + OFF_WKB);
  u16* QB     = (u16*)(ws + OFF_QB);
  u16* KB     = (u16*)(ws + OFF_KB);
  u16* oTB    = (u16*)(ws + OFF_OTB);
  u16* P      = (u16*)(ws + OFF_P);
  float* S    = (float*)(ws + OFF_S);
  u16* scaled = (u16*)(ws + OFF_SCALED);
  bool use_scaled = (ws_size >= NEED_SCALED);

  // 1) bf16 conversions
  cvt_bf16<<<1024, 256, 0, stream>>>(main_feat, mainB, 2048 * 512);
  cvt_bf16<<<1024, 256, 0, stream>>>(other_feat, otherB, 2048 * 512);
  cvt_bf16<<<256, 256, 0, stream>>>(Wq, WqB, 512 * 512);
  cvt_bf16<<<256, 256, 0, stream>>>(Wk, WkB, 512 * 512);
  // 2) otherT bf16 [512][2048]
  transpose_cvt<<<dim3(16, 64), 256, 0, stream>>>(other_feat, oTB, 2048, 512);

  if (use_scaled) {
    // 3) fused Q|K projection
    gemm_lds<0><<<dim3(4, 32), 256, 0, stream>>>(mainB, WqB, bq, WkB, bk,
        nullptr, QB, 4096, 512, 512);
    // 4) S = Q @ K^T
    gemm_lds<1><<<dim3(16, 16), 256, 0, stream>>>(QB, KB, nullptr, nullptr, nullptr,
        S, nullptr, 2048, 2048, 512);
    // 5) masked softmax -> P bf16
    softmax_mask<<<2048, 256, 0, stream>>>(S, mask, P, 2048);
    // 6) scaled as Bt [16384][2048]
    build_scaled<<<32768, 256, 0, stream>>>(oTB, fix_feat, scaled);
    // 7) 8-phase pipelined GEMM: out[b][m][k] via col scatter
    gemm_ring<<<dim3(8, 64), 512, 0, stream>>>(P, scaled, out, 2048, 16384, 2048);
  } else {
    gemm_bt<0><<<dim3(4, 16, 1), 256, 0, stream>>>(mainB, WqB, bq, nullptr,
        nullptr, QB, 2048, 512, 512, 0, 0);
    gemm_bt<0><<<dim3(4, 16, 1), 256, 0, stream>>>(otherB, WkB, bk, nullptr,
        nullptr, KB, 2048, 512, 512, 0, 0);
    gemm_bt<1><<<dim3(16, 16, 1), 256, 0, stream>>>(QB, KB, nullptr, nullptr,
        S, nullptr, 2048, 2048, 512, 0, 0);
    softmax_mask<<<2048, 256, 0, stream>>>(S, mask, P, 2048);
    gemm_bt<2><<<dim3(4, 16, BATCH_), 256, 0, stream>>>(P, oTB, nullptr, fix_feat,
        out, nullptr, 2048, 512, 2048, 1048576LL, 0);
  }
}